// Round 12
// baseline (156.131 us; speedup 1.0000x reference)
//
#include <hip/hip_runtime.h>

constexpr int N    = 50000;
constexpr int E    = 800000;
constexpr int CIN  = 128;
constexpr int COUT = 64;
constexpr float SELF_LOOP_W = 2.0f;

constexpr int NB   = (N + 63) / 64;   // 782 buckets of 64 nodes
constexpr int CAP  = 1536;            // slots/bucket (mean 1023, sigma 32)
constexpr int EPB  = 2048;            // edges per partition block
constexpr int PBLK = (E + EPB - 1) / EPB;   // 391

typedef float          vfloat4  __attribute__((ext_vector_type(4)));
typedef int            vint2    __attribute__((ext_vector_type(2)));
typedef unsigned short vushort4 __attribute__((ext_vector_type(4)));

// round-to-nearest-even fp32 -> bf16
__device__ __forceinline__ unsigned short f2bf(float f) {
    unsigned int u = __float_as_uint(f);
    u += 0x7FFFu + ((u >> 16) & 1u);
    return (unsigned short)(u >> 16);
}
__device__ __forceinline__ float bf2f(unsigned short h) {
    return __uint_as_float(((unsigned int)h) << 16);
}

// ---------------------------------------------------------------------------
__global__ void init_kernel(int* __restrict__ bcur) {
    int i = blockIdx.x * blockDim.x + threadIdx.x;
    if (i < NB) bcur[i] = i * CAP;
}

// ---------------------------------------------------------------------------
// single-pass radix partition: one read of row/col/ew, LDS-staged records,
// then per-bucket contiguous scatter. pk[p] = {row | (c&63)<<20, bits(ew)}.
__global__ __launch_bounds__(512) void partition_kernel(const int* __restrict__ row,
                                                        const int* __restrict__ col,
                                                        const float* __restrict__ ew,
                                                        int* __restrict__ bcur,
                                                        vint2* __restrict__ pk) {
    __shared__ vint2 srec[EPB];         // 16 KB staged records
    __shared__ short sbkt[EPB];         // 4 KB bucket id per record
    __shared__ int   lhist[NB];         // 3.1 KB
    __shared__ int   lbase[NB];         // 3.1 KB

    const int t  = threadIdx.x;
    const int e0 = blockIdx.x * EPB;
    const int m  = min(EPB, E - e0);    // records this block

    for (int i = t; i < NB; i += 512) lhist[i] = 0;
    __syncthreads();

    // stage + histogram (single global read of the edge list)
    #pragma unroll
    for (int k = 0; k < EPB / 512; ++k) {
        int j = k * 512 + t;
        int e = e0 + j;
        if (j < m) {
            int c   = col[e];
            int bkt = c >> 6;
            vint2 v;
            v.x = row[e] | ((c & 63) << 20);
            v.y = __float_as_int(ew[e]);
            srec[j] = v;
            sbkt[j] = (short)bkt;
            atomicAdd(&lhist[bkt], 1);
        }
    }
    __syncthreads();

    // reserve global ranges per bucket; reuse lhist as local cursor
    for (int i = t; i < NB; i += 512) {
        int h = lhist[i];
        lbase[i] = (h > 0) ? atomicAdd(&bcur[i], h) : 0;
    }
    __syncthreads();
    for (int i = t; i < NB; i += 512) lhist[i] = 0;
    __syncthreads();

    // scatter from LDS (runs of same bucket fill lines in pk)
    #pragma unroll
    for (int k = 0; k < EPB / 512; ++k) {
        int j = k * 512 + t;
        if (j < m) {
            int bkt = sbkt[j];
            int p = lbase[bkt] + atomicAdd(&lhist[bkt], 1);
            if (p < (bkt + 1) * CAP)    // capacity guard
                pk[p] = srec[j];
        }
    }
}

// ---------------------------------------------------------------------------
// per-bucket degree -> dinv  (dinv[c] = rsqrt(2 + sum ew))
__global__ __launch_bounds__(256) void deg_kernel(const int* __restrict__ bcur,
                                                  const vint2* __restrict__ pk,
                                                  float* __restrict__ dinv) {
    __shared__ float ldeg[64];
    const int t    = threadIdx.x;
    const int b    = blockIdx.x;
    const int base = b * CAP;
    const int cnt  = min(bcur[b] - base, CAP);

    if (t < 64) ldeg[t] = 0.f;
    __syncthreads();
    for (int j = t; j < cnt; j += 256) {
        vint2 v = pk[base + j];
        atomicAdd(&ldeg[(v.x >> 20) & 63], __int_as_float(v.y));
    }
    __syncthreads();
    int node = b * 64 + t;
    if (t < 64 && node < N) dinv[node] = rsqrtf(SELF_LOOP_W + ldeg[t]);
}

// ---------------------------------------------------------------------------
// GEMM: xwh = bf16(x @ W)  (64x64 tile, 4x4 per thread)
__global__ __launch_bounds__(256) void xw_kernel(const float* __restrict__ x,
                                                 const float* __restrict__ W,
                                                 unsigned short* __restrict__ xwh) {
    __shared__ __align__(16) float xs[64][132];

    const int t    = threadIdx.x;
    const int base = blockIdx.x * 64;

    #pragma unroll
    for (int i = 0; i < 8; ++i) {
        int f4  = i * 256 + t;
        int r   = f4 >> 5;
        int c4  = f4 & 31;
        int node = base + r;
        if (node >= N) node = N - 1;
        vfloat4 v = *(const vfloat4*)(x + (size_t)node * CIN + c4 * 4);
        *(vfloat4*)&xs[r][c4 * 4] = v;
    }
    __syncthreads();

    const int tc = t & 15;
    const int tn = t >> 4;

    float acc[4][4];
    #pragma unroll
    for (int i = 0; i < 4; ++i)
        #pragma unroll
        for (int j = 0; j < 4; ++j) acc[i][j] = 0.f;

    const float* Wp = W + tc * 4;
    #pragma unroll 8
    for (int k = 0; k < CIN; ++k) {
        vfloat4 bv = *(const vfloat4*)(Wp + (size_t)k * COUT);
        float a0 = xs[tn * 4 + 0][k];
        float a1 = xs[tn * 4 + 1][k];
        float a2 = xs[tn * 4 + 2][k];
        float a3 = xs[tn * 4 + 3][k];
        #pragma unroll
        for (int j = 0; j < 4; ++j) {
            acc[0][j] += a0 * bv[j];
            acc[1][j] += a1 * bv[j];
            acc[2][j] += a2 * bv[j];
            acc[3][j] += a3 * bv[j];
        }
    }

    #pragma unroll
    for (int i = 0; i < 4; ++i) {
        int node = base + tn * 4 + i;
        if (node >= N) continue;
        vushort4 hv;
        #pragma unroll
        for (int j = 0; j < 4; ++j) hv[j] = f2bf(acc[i][j]);
        *(vushort4*)(xwh + (size_t)node * COUT + tc * 4) = hv;
    }
}

// ---------------------------------------------------------------------------
// per-bucket: pk -> LDS stage + counting-sort, then atomic-free per-node
// register accumulation over bf16 xw gather; self-loop+bias epilogue.
__global__ __launch_bounds__(512) void aggregate_kernel(const int* __restrict__ bcur,
                                                        const vint2* __restrict__ pk,
                                                        const float* __restrict__ dinv,
                                                        const unsigned short* __restrict__ xwh,
                                                        const float* __restrict__ bias,
                                                        float* __restrict__ out) {
    __shared__ int   rawx[CAP];      // raw: row | ln<<20
    __shared__ float rawn[CAP];      // raw: ew * dinv[row]
    __shared__ int   s_r[CAP];       // sorted: row
    __shared__ float s_n[CAP];       // sorted: norm
    __shared__ int   lhist[64], lofs[64], lcur[64];

    const int t    = threadIdx.x;
    const int lane = t & 63;
    const int wv   = t >> 6;          // 0..7
    const int b    = blockIdx.x;
    const int base = b * CAP;
    const int cnt  = min(bcur[b] - base, CAP);

    if (t < 64) lhist[t] = 0;
    __syncthreads();

    // stage + histogram (one coalesced pk read, 512 parallel dinv loads)
    for (int j = t; j < cnt; j += 512) {
        vint2 v = pk[base + j];
        rawx[j] = v.x;
        rawn[j] = __int_as_float(v.y) * dinv[v.x & 0xFFFFF];
        atomicAdd(&lhist[(v.x >> 20) & 63], 1);
    }
    __syncthreads();

    // wave 0: exclusive prefix scan of the 64 counters
    if (t < 64) {
        int v = lhist[t];
        int s = v;
        #pragma unroll
        for (int d = 1; d < 64; d <<= 1) {
            int u = __shfl_up(s, d);
            if (lane >= d) s += u;
        }
        lofs[t] = s - v;
        lcur[t] = s - v;
    }
    __syncthreads();

    // counting-sort scatter (LDS -> LDS)
    for (int j = t; j < cnt; j += 512) {
        int xv = rawx[j];
        int p  = atomicAdd(&lcur[(xv >> 20) & 63], 1);
        s_r[p] = xv & 0xFFFFF;
        s_n[p] = rawn[j];
    }
    __syncthreads();

    // per-node register accumulation — NO atomics between xwh loads
    float bl = bias[lane];
    for (int nd = wv; nd < 64; nd += 8) {
        int node = b * 64 + nd;
        if (node >= N) continue;              // wave-uniform branch
        int s0 = lofs[nd];
        int e0 = s0 + lhist[nd];
        float acc = 0.f;
        int i = s0;
        for (; i + 8 <= e0; i += 8) {
            int r[8]; float n[8], v[8];
            #pragma unroll
            for (int u = 0; u < 8; ++u) { r[u] = s_r[i + u]; n[u] = s_n[i + u]; }
            #pragma unroll
            for (int u = 0; u < 8; ++u)
                v[u] = bf2f(xwh[(size_t)r[u] * COUT + lane]);   // 8 gathers in flight
            #pragma unroll
            for (int u = 0; u < 8; ++u) acc += n[u] * v[u];
        }
        for (; i < e0; ++i)
            acc += s_n[i] * bf2f(xwh[(size_t)s_r[i] * COUT + lane]);

        float dc = dinv[node];
        float xv = bf2f(xwh[(size_t)node * COUT + lane]);
        out[(size_t)node * COUT + lane] =
            dc * acc + SELF_LOOP_W * dc * dc * xv + bl;
    }
}

// ---------------------------------------------------------------------------
extern "C" void kernel_launch(void* const* d_in, const int* in_sizes, int n_in,
                              void* d_out, int out_size, void* d_ws, size_t ws_size,
                              hipStream_t stream) {
    const float* x  = (const float*)d_in[0];
    const int*   ei = (const int*)d_in[1];   // [2, E] int32
    const float* ew = (const float*)d_in[2];
    const float* W  = (const float*)d_in[3];
    const float* b  = (const float*)d_in[4];
    float* out = (float*)d_out;

    // ws layout
    unsigned short* xwh  = (unsigned short*)d_ws;            // N*COUT bf16 (6.4 MB)
    float*          dinv = (float*)(xwh + (size_t)N * COUT); // N
    int*            bcur = (int*)(dinv + N);                 // NB
    vint2*          pk   = (vint2*)(bcur + NB + 2);          // NB*CAP records (9.6 MB)

    const int* rowp = ei;
    const int* colp = ei + E;

    init_kernel     <<<(NB + 255) / 256, 256, 0, stream>>>(bcur);
    partition_kernel<<<PBLK, 512, 0, stream>>>(rowp, colp, ew, bcur, pk);
    xw_kernel       <<<NB, 256, 0, stream>>>(x, W, xwh);
    deg_kernel      <<<NB, 256, 0, stream>>>(bcur, pk, dinv);
    aggregate_kernel<<<NB, 512, 0, stream>>>(bcur, pk, dinv, xwh, b, out);
}

// Round 13
// 147.917 us; speedup vs baseline: 1.0555x; 1.0555x over previous
//
#include <hip/hip_runtime.h>

constexpr int N    = 50000;
constexpr int E    = 800000;
constexpr int CIN  = 128;
constexpr int COUT = 64;
constexpr float SELF_LOOP_W = 2.0f;

constexpr int NB   = (N + 63) / 64;   // 782 buckets of 64 nodes
constexpr int CAP  = 1536;            // slots/bucket (mean 1023, sigma 32)
constexpr int EPB  = 4096;            // edges per partition block
constexpr int PBLK = (E + EPB - 1) / EPB;   // 196

typedef float          vfloat4  __attribute__((ext_vector_type(4)));
typedef float          vfloat2  __attribute__((ext_vector_type(2)));
typedef int            vint2    __attribute__((ext_vector_type(2)));
typedef unsigned short vushort4 __attribute__((ext_vector_type(4)));

// round-to-nearest-even fp32 -> bf16
__device__ __forceinline__ unsigned short f2bf(float f) {
    unsigned int u = __float_as_uint(f);
    u += 0x7FFFu + ((u >> 16) & 1u);
    return (unsigned short)(u >> 16);
}
__device__ __forceinline__ float bf2f(unsigned short h) {
    return __uint_as_float(((unsigned int)h) << 16);
}
// unpack packed ushort2 (as uint) -> two floats
__device__ __forceinline__ vfloat2 bf2x(unsigned int u) {
    vfloat2 f;
    f.x = __uint_as_float(u << 16);
    f.y = __uint_as_float(u & 0xFFFF0000u);
    return f;
}

// ---------------------------------------------------------------------------
__global__ void init_kernel(int* __restrict__ bcur) {
    int i = blockIdx.x * blockDim.x + threadIdx.x;
    if (i < NB) bcur[i] = i * CAP;
}

// ---------------------------------------------------------------------------
// two-pass radix partition (R11 proven): pk[p] = {row | (c&63)<<20, bits(ew)}
__global__ __launch_bounds__(512) void partition_kernel(const int* __restrict__ row,
                                                        const int* __restrict__ col,
                                                        const float* __restrict__ ew,
                                                        int* __restrict__ bcur,
                                                        vint2* __restrict__ pk) {
    __shared__ int lhist[NB];
    __shared__ int lbase[NB];
    const int t  = threadIdx.x;
    const int e0 = blockIdx.x * EPB;

    for (int i = t; i < NB; i += 512) lhist[i] = 0;
    __syncthreads();

    #pragma unroll
    for (int k = 0; k < EPB / 512; ++k) {
        int e = e0 + k * 512 + t;
        if (e < E) atomicAdd(&lhist[col[e] >> 6], 1);
    }
    __syncthreads();

    for (int i = t; i < NB; i += 512) {
        int h = lhist[i];
        lbase[i] = (h > 0) ? atomicAdd(&bcur[i], h) : 0;
    }
    __syncthreads();
    for (int i = t; i < NB; i += 512) lhist[i] = 0;
    __syncthreads();

    #pragma unroll
    for (int k = 0; k < EPB / 512; ++k) {
        int e = e0 + k * 512 + t;
        if (e < E) {
            int c   = col[e];
            int bkt = c >> 6;
            int p = lbase[bkt] + atomicAdd(&lhist[bkt], 1);
            if (p < (bkt + 1) * CAP) {          // capacity guard
                vint2 v;
                v.x = row[e] | ((c & 63) << 20);
                v.y = __float_as_int(ew[e]);
                pk[p] = v;
            }
        }
    }
}

// ---------------------------------------------------------------------------
// per-bucket degree -> dinv  (dinv[c] = rsqrt(2 + sum ew))
__global__ __launch_bounds__(256) void deg_kernel(const int* __restrict__ bcur,
                                                  const vint2* __restrict__ pk,
                                                  float* __restrict__ dinv) {
    __shared__ float ldeg[64];
    const int t    = threadIdx.x;
    const int b    = blockIdx.x;
    const int base = b * CAP;
    const int cnt  = min(bcur[b] - base, CAP);

    if (t < 64) ldeg[t] = 0.f;
    __syncthreads();
    for (int j = t; j < cnt; j += 256) {
        vint2 v = pk[base + j];
        atomicAdd(&ldeg[(v.x >> 20) & 63], __int_as_float(v.y));
    }
    __syncthreads();
    int node = b * 64 + t;
    if (t < 64 && node < N) dinv[node] = rsqrtf(SELF_LOOP_W + ldeg[t]);
}

// ---------------------------------------------------------------------------
// GEMM: xwh = bf16(x @ W)  (64x64 tile, 4x4 per thread)
__global__ __launch_bounds__(256) void xw_kernel(const float* __restrict__ x,
                                                 const float* __restrict__ W,
                                                 unsigned short* __restrict__ xwh) {
    __shared__ __align__(16) float xs[64][132];

    const int t    = threadIdx.x;
    const int base = blockIdx.x * 64;

    #pragma unroll
    for (int i = 0; i < 8; ++i) {
        int f4  = i * 256 + t;
        int r   = f4 >> 5;
        int c4  = f4 & 31;
        int node = base + r;
        if (node >= N) node = N - 1;
        vfloat4 v = *(const vfloat4*)(x + (size_t)node * CIN + c4 * 4);
        *(vfloat4*)&xs[r][c4 * 4] = v;
    }
    __syncthreads();

    const int tc = t & 15;
    const int tn = t >> 4;

    float acc[4][4];
    #pragma unroll
    for (int i = 0; i < 4; ++i)
        #pragma unroll
        for (int j = 0; j < 4; ++j) acc[i][j] = 0.f;

    const float* Wp = W + tc * 4;
    #pragma unroll 8
    for (int k = 0; k < CIN; ++k) {
        vfloat4 bv = *(const vfloat4*)(Wp + (size_t)k * COUT);
        float a0 = xs[tn * 4 + 0][k];
        float a1 = xs[tn * 4 + 1][k];
        float a2 = xs[tn * 4 + 2][k];
        float a3 = xs[tn * 4 + 3][k];
        #pragma unroll
        for (int j = 0; j < 4; ++j) {
            acc[0][j] += a0 * bv[j];
            acc[1][j] += a1 * bv[j];
            acc[2][j] += a2 * bv[j];
            acc[3][j] += a3 * bv[j];
        }
    }

    #pragma unroll
    for (int i = 0; i < 4; ++i) {
        int node = base + tn * 4 + i;
        if (node >= N) continue;
        vushort4 hv;
        #pragma unroll
        for (int j = 0; j < 4; ++j) hv[j] = f2bf(acc[i][j]);
        *(vushort4*)(xwh + (size_t)node * COUT + tc * 4) = hv;
    }
}

// ---------------------------------------------------------------------------
// per-bucket: pk -> LDS counting-sort, then atomic-free per-node accumulation
// with HALF-WAVE PAIRING: lane = (rec half, ch pair); one ushort2 load serves
// 2 channels; wave processes 2 records per load slot (16 recs in flight).
__global__ __launch_bounds__(512) void aggregate_kernel(const int* __restrict__ bcur,
                                                        const vint2* __restrict__ pk,
                                                        const float* __restrict__ dinv,
                                                        const unsigned short* __restrict__ xwh,
                                                        const float* __restrict__ bias,
                                                        float* __restrict__ out) {
    __shared__ int   rawx[CAP];      // raw: row | ln<<20
    __shared__ float rawn[CAP];      // raw: ew * dinv[row]
    __shared__ int   s_r[CAP];       // sorted: row
    __shared__ float s_n[CAP];       // sorted: norm
    __shared__ int   lhist[64], lofs[64], lcur[64];

    const int t    = threadIdx.x;
    const int lane = t & 63;
    const int wv   = t >> 6;          // 0..7
    const int b    = blockIdx.x;
    const int base = b * CAP;
    const int cnt  = min(bcur[b] - base, CAP);

    if (t < 64) lhist[t] = 0;
    __syncthreads();

    // stage + histogram (coalesced pk read, 512 parallel dinv loads)
    for (int j = t; j < cnt; j += 512) {
        vint2 v = pk[base + j];
        rawx[j] = v.x;
        rawn[j] = __int_as_float(v.y) * dinv[v.x & 0xFFFFF];
        atomicAdd(&lhist[(v.x >> 20) & 63], 1);
    }
    __syncthreads();

    // wave 0: exclusive prefix scan of the 64 counters
    if (t < 64) {
        int v = lhist[t];
        int s = v;
        #pragma unroll
        for (int d = 1; d < 64; d <<= 1) {
            int u = __shfl_up(s, d);
            if (lane >= d) s += u;
        }
        lofs[t] = s - v;
        lcur[t] = s - v;
    }
    __syncthreads();

    // counting-sort scatter (LDS -> LDS)
    for (int j = t; j < cnt; j += 512) {
        int xv = rawx[j];
        int p  = atomicAdd(&lcur[(xv >> 20) & 63], 1);
        s_r[p] = xv & 0xFFFFF;
        s_n[p] = rawn[j];
    }
    __syncthreads();

    // per-node accumulation: half-wave pairing, no atomics between loads
    const int half = lane >> 5;       // 0 or 1: which record of the pair
    const int c2   = lane & 31;       // channel pair: channels 2*c2, 2*c2+1

    for (int nd = wv; nd < 64; nd += 8) {
        int node = b * 64 + nd;
        if (node >= N) continue;      // wave-uniform
        int s0 = lofs[nd];
        int e0 = s0 + lhist[nd];
        float ax = 0.f, ay = 0.f;

        for (int i = s0; i < e0; i += 16) {
            int rr[8]; float nn[8]; unsigned int vv[8];
            #pragma unroll
            for (int u = 0; u < 8; ++u) {
                int j = i + 2 * u + half;
                bool ok = (j < e0);
                rr[u] = ok ? s_r[j] : s_r[s0];
                nn[u] = ok ? s_n[j] : 0.f;
            }
            #pragma unroll
            for (int u = 0; u < 8; ++u)
                vv[u] = *(const unsigned int*)(xwh + (size_t)rr[u] * COUT + c2 * 2);
            #pragma unroll
            for (int u = 0; u < 8; ++u) {
                vfloat2 f = bf2x(vv[u]);
                ax += nn[u] * f.x;
                ay += nn[u] * f.y;
            }
        }
        // combine the two record-halves
        ax += __shfl_xor(ax, 32);
        ay += __shfl_xor(ay, 32);

        if (half == 0) {              // lanes 0..31 write float2 (256B row)
            float dc = dinv[node];
            unsigned int su = *(const unsigned int*)(xwh + (size_t)node * COUT + c2 * 2);
            vfloat2 sf = bf2x(su);
            vfloat2 o;
            o.x = dc * ax + SELF_LOOP_W * dc * dc * sf.x + bias[c2 * 2];
            o.y = dc * ay + SELF_LOOP_W * dc * dc * sf.y + bias[c2 * 2 + 1];
            *(vfloat2*)(out + (size_t)node * COUT + c2 * 2) = o;
        }
    }
}

// ---------------------------------------------------------------------------
extern "C" void kernel_launch(void* const* d_in, const int* in_sizes, int n_in,
                              void* d_out, int out_size, void* d_ws, size_t ws_size,
                              hipStream_t stream) {
    const float* x  = (const float*)d_in[0];
    const int*   ei = (const int*)d_in[1];   // [2, E] int32
    const float* ew = (const float*)d_in[2];
    const float* W  = (const float*)d_in[3];
    const float* b  = (const float*)d_in[4];
    float* out = (float*)d_out;

    // ws layout
    unsigned short* xwh  = (unsigned short*)d_ws;            // N*COUT bf16 (6.4 MB)
    float*          dinv = (float*)(xwh + (size_t)N * COUT); // N
    int*            bcur = (int*)(dinv + N);                 // NB
    vint2*          pk   = (vint2*)(bcur + NB + 2);          // NB*CAP records (9.6 MB)

    const int* rowp = ei;
    const int* colp = ei + E;

    init_kernel     <<<(NB + 255) / 256, 256, 0, stream>>>(bcur);
    partition_kernel<<<PBLK, 512, 0, stream>>>(rowp, colp, ew, bcur, pk);
    xw_kernel       <<<NB, 256, 0, stream>>>(x, W, xwh);
    deg_kernel      <<<NB, 256, 0, stream>>>(bcur, pk, dinv);
    aggregate_kernel<<<NB, 512, 0, stream>>>(bcur, pk, dinv, xwh, b, out);
}

// Round 14
// 146.639 us; speedup vs baseline: 1.0647x; 1.0087x over previous
//
#include <hip/hip_runtime.h>

constexpr int N    = 50000;
constexpr int E    = 800000;
constexpr int CIN  = 128;
constexpr int COUT = 64;
constexpr float SELF_LOOP_W = 2.0f;

constexpr int NB   = (N + 63) / 64;   // 782 buckets of 64 nodes
constexpr int CAP  = 1536;            // slots/bucket (mean 1023, sigma 32)
constexpr int EPB  = 4096;            // edges per partition block
constexpr int PBLK = (E + EPB - 1) / EPB;   // 196

typedef float          vfloat4  __attribute__((ext_vector_type(4)));
typedef int            vint2    __attribute__((ext_vector_type(2)));
typedef unsigned short vushort4 __attribute__((ext_vector_type(4)));

// round-to-nearest-even fp32 -> bf16
__device__ __forceinline__ unsigned short f2bf(float f) {
    unsigned int u = __float_as_uint(f);
    u += 0x7FFFu + ((u >> 16) & 1u);
    return (unsigned short)(u >> 16);
}
__device__ __forceinline__ float bf2f(unsigned short h) {
    return __uint_as_float(((unsigned int)h) << 16);
}

// ---------------------------------------------------------------------------
// two-pass radix partition; bcur zeroed by memset, cursors bucket-relative.
// pk[p] = {row | (c&63)<<20, bits(ew)}
__global__ __launch_bounds__(512) void partition_kernel(const int* __restrict__ row,
                                                        const int* __restrict__ col,
                                                        const float* __restrict__ ew,
                                                        int* __restrict__ bcur,
                                                        vint2* __restrict__ pk) {
    __shared__ int lhist[NB];
    __shared__ int lbase[NB];
    const int t  = threadIdx.x;
    const int e0 = blockIdx.x * EPB;

    for (int i = t; i < NB; i += 512) lhist[i] = 0;
    __syncthreads();

    #pragma unroll
    for (int k = 0; k < EPB / 512; ++k) {
        int e = e0 + k * 512 + t;
        if (e < E) atomicAdd(&lhist[col[e] >> 6], 1);
    }
    __syncthreads();

    for (int i = t; i < NB; i += 512) {
        int h = lhist[i];
        if (h > 0) lbase[i] = i * CAP + atomicAdd(&bcur[i], h);
    }
    __syncthreads();
    for (int i = t; i < NB; i += 512) lhist[i] = 0;
    __syncthreads();

    #pragma unroll
    for (int k = 0; k < EPB / 512; ++k) {
        int e = e0 + k * 512 + t;
        if (e < E) {
            int c   = col[e];
            int bkt = c >> 6;
            int p = lbase[bkt] + atomicAdd(&lhist[bkt], 1);
            if (p < (bkt + 1) * CAP) {          // capacity guard
                vint2 v;
                v.x = row[e] | ((c & 63) << 20);
                v.y = __float_as_int(ew[e]);
                pk[p] = v;
            }
        }
    }
}

// ---------------------------------------------------------------------------
// fused: xwh = bf16(x @ W) (64x64 tile, 4x4/thread) THEN per-bucket deg->dinv
__global__ __launch_bounds__(256) void xw_deg_kernel(const float* __restrict__ x,
                                                     const float* __restrict__ W,
                                                     const int* __restrict__ bcur,
                                                     const vint2* __restrict__ pk,
                                                     unsigned short* __restrict__ xwh,
                                                     float* __restrict__ dinv) {
    __shared__ __align__(16) float xs[64][132];
    __shared__ float ldeg[64];

    const int t    = threadIdx.x;
    const int b    = blockIdx.x;
    const int base = b * 64;

    // ---- GEMM phase ----
    #pragma unroll
    for (int i = 0; i < 8; ++i) {
        int f4  = i * 256 + t;
        int r   = f4 >> 5;
        int c4  = f4 & 31;
        int node = base + r;
        if (node >= N) node = N - 1;
        vfloat4 v = *(const vfloat4*)(x + (size_t)node * CIN + c4 * 4);
        *(vfloat4*)&xs[r][c4 * 4] = v;
    }
    if (t < 64) ldeg[t] = 0.f;
    __syncthreads();

    const int tc = t & 15;
    const int tn = t >> 4;

    float acc[4][4];
    #pragma unroll
    for (int i = 0; i < 4; ++i)
        #pragma unroll
        for (int j = 0; j < 4; ++j) acc[i][j] = 0.f;

    const float* Wp = W + tc * 4;
    #pragma unroll 8
    for (int k = 0; k < CIN; ++k) {
        vfloat4 bv = *(const vfloat4*)(Wp + (size_t)k * COUT);
        float a0 = xs[tn * 4 + 0][k];
        float a1 = xs[tn * 4 + 1][k];
        float a2 = xs[tn * 4 + 2][k];
        float a3 = xs[tn * 4 + 3][k];
        #pragma unroll
        for (int j = 0; j < 4; ++j) {
            acc[0][j] += a0 * bv[j];
            acc[1][j] += a1 * bv[j];
            acc[2][j] += a2 * bv[j];
            acc[3][j] += a3 * bv[j];
        }
    }

    #pragma unroll
    for (int i = 0; i < 4; ++i) {
        int node = base + tn * 4 + i;
        if (node >= N) continue;
        vushort4 hv;
        #pragma unroll
        for (int j = 0; j < 4; ++j) hv[j] = f2bf(acc[i][j]);
        *(vushort4*)(xwh + (size_t)node * COUT + tc * 4) = hv;
    }

    // ---- deg phase (same bucket) ----
    const int pbase = b * CAP;
    const int cnt   = min(bcur[b], CAP);
    for (int j = t; j < cnt; j += 256) {
        vint2 v = pk[pbase + j];
        atomicAdd(&ldeg[(v.x >> 20) & 63], __int_as_float(v.y));
    }
    __syncthreads();
    int node = base + t;
    if (t < 64 && node < N) dinv[node] = rsqrtf(SELF_LOOP_W + ldeg[t]);
}

// ---------------------------------------------------------------------------
// per-bucket: pk -> LDS counting-sort, then atomic-free per-node accumulation
// with QUARTER-WAVE pairing: lane = (record quarter q, channel quad c4);
// one ushort4 load serves 4 channels; 16 records per batch; combine via
// shfl_xor(16)+shfl_xor(32); q=0 lanes write float4 (coalesced row).
__global__ __launch_bounds__(512) void aggregate_kernel(const int* __restrict__ bcur,
                                                        const vint2* __restrict__ pk,
                                                        const float* __restrict__ dinv,
                                                        const unsigned short* __restrict__ xwh,
                                                        const float* __restrict__ bias,
                                                        float* __restrict__ out) {
    __shared__ int   rawx[CAP];      // raw: row | ln<<20
    __shared__ float rawn[CAP];      // raw: ew * dinv[row]
    __shared__ int   s_r[CAP];       // sorted: row
    __shared__ float s_n[CAP];       // sorted: norm
    __shared__ int   lhist[64], lofs[64], lcur[64];

    const int t    = threadIdx.x;
    const int lane = t & 63;
    const int wv   = t >> 6;          // 0..7
    const int b    = blockIdx.x;
    const int base = b * CAP;
    const int cnt  = min(bcur[b], CAP);

    if (t < 64) lhist[t] = 0;
    __syncthreads();

    // stage + histogram (coalesced pk read, 512 parallel dinv loads)
    for (int j = t; j < cnt; j += 512) {
        vint2 v = pk[base + j];
        rawx[j] = v.x;
        rawn[j] = __int_as_float(v.y) * dinv[v.x & 0xFFFFF];
        atomicAdd(&lhist[(v.x >> 20) & 63], 1);
    }
    __syncthreads();

    // wave 0: exclusive prefix scan of the 64 counters
    if (t < 64) {
        int v = lhist[t];
        int s = v;
        #pragma unroll
        for (int d = 1; d < 64; d <<= 1) {
            int u = __shfl_up(s, d);
            if (lane >= d) s += u;
        }
        lofs[t] = s - v;
        lcur[t] = s - v;
    }
    __syncthreads();

    // counting-sort scatter (LDS -> LDS)
    for (int j = t; j < cnt; j += 512) {
        int xv = rawx[j];
        int p  = atomicAdd(&lcur[(xv >> 20) & 63], 1);
        s_r[p] = xv & 0xFFFFF;
        s_n[p] = rawn[j];
    }
    __syncthreads();

    const int q  = lane >> 4;        // record quarter 0..3
    const int c4 = lane & 15;        // channel quad: channels c4*4 .. +3

    for (int nd = wv; nd < 64; nd += 8) {
        int node = b * 64 + nd;
        if (node >= N) continue;     // wave-uniform
        int s0 = lofs[nd];
        int e0 = s0 + lhist[nd];

        float a0 = 0.f, a1 = 0.f, a2 = 0.f, a3 = 0.f;
        for (int i = s0; i < e0; i += 16) {
            int rr[4]; float nn[4]; vushort4 vv[4];
            #pragma unroll
            for (int u = 0; u < 4; ++u) {
                int j = i + 4 * u + q;
                bool ok = (j < e0);
                rr[u] = ok ? s_r[j] : s_r[s0];
                nn[u] = ok ? s_n[j] : 0.f;
            }
            #pragma unroll
            for (int u = 0; u < 4; ++u)
                vv[u] = *(const vushort4*)(xwh + (size_t)rr[u] * COUT + c4 * 4);
            #pragma unroll
            for (int u = 0; u < 4; ++u) {
                a0 += nn[u] * bf2f(vv[u][0]);
                a1 += nn[u] * bf2f(vv[u][1]);
                a2 += nn[u] * bf2f(vv[u][2]);
                a3 += nn[u] * bf2f(vv[u][3]);
            }
        }
        // combine the four record-quarters
        a0 += __shfl_xor(a0, 16); a0 += __shfl_xor(a0, 32);
        a1 += __shfl_xor(a1, 16); a1 += __shfl_xor(a1, 32);
        a2 += __shfl_xor(a2, 16); a2 += __shfl_xor(a2, 32);
        a3 += __shfl_xor(a3, 16); a3 += __shfl_xor(a3, 32);

        if (q == 0) {                // lanes 0..15 write float4 (256B row)
            float dc = dinv[node];
            float s2 = SELF_LOOP_W * dc * dc;
            vushort4 sh = *(const vushort4*)(xwh + (size_t)node * COUT + c4 * 4);
            vfloat4  bv = *(const vfloat4*)(bias + c4 * 4);
            vfloat4  o;
            o[0] = dc * a0 + s2 * bf2f(sh[0]) + bv[0];
            o[1] = dc * a1 + s2 * bf2f(sh[1]) + bv[1];
            o[2] = dc * a2 + s2 * bf2f(sh[2]) + bv[2];
            o[3] = dc * a3 + s2 * bf2f(sh[3]) + bv[3];
            *(vfloat4*)(out + (size_t)node * COUT + c4 * 4) = o;
        }
    }
}

// ---------------------------------------------------------------------------
extern "C" void kernel_launch(void* const* d_in, const int* in_sizes, int n_in,
                              void* d_out, int out_size, void* d_ws, size_t ws_size,
                              hipStream_t stream) {
    const float* x  = (const float*)d_in[0];
    const int*   ei = (const int*)d_in[1];   // [2, E] int32
    const float* ew = (const float*)d_in[2];
    const float* W  = (const float*)d_in[3];
    const float* b  = (const float*)d_in[4];
    float* out = (float*)d_out;

    // ws layout
    unsigned short* xwh  = (unsigned short*)d_ws;            // N*COUT bf16 (6.4 MB)
    float*          dinv = (float*)(xwh + (size_t)N * COUT); // N
    int*            bcur = (int*)(dinv + N);                 // NB
    vint2*          pk   = (vint2*)(bcur + NB + 2);          // NB*CAP records (9.6 MB)

    const int* rowp = ei;
    const int* colp = ei + E;

    hipMemsetAsync(bcur, 0, NB * sizeof(int), stream);
    partition_kernel<<<PBLK, 512, 0, stream>>>(rowp, colp, ew, bcur, pk);
    xw_deg_kernel   <<<NB, 256, 0, stream>>>(x, W, bcur, pk, xwh, dinv);
    aggregate_kernel<<<NB, 512, 0, stream>>>(bcur, pk, dinv, xwh, b, out);
}